// Round 1
// baseline (541.089 us; speedup 1.0000x reference)
//
#include <hip/hip_runtime.h>

#define Bq 4
#define Nq 512
#define Dq 128

constexpr float LEAKY = 0.01f;
constexpr float LN_EPS = 1e-5f;

// ---------------- Kernel 1: LayerNorm + attention scores ----------------
// One wave (64 lanes) per (b,n) row; lane handles 2 of the D=128 elements.
// Block = 256 threads = 4 rows.
__global__ void __launch_bounds__(256) scores_kernel(
    const float* __restrict__ emb, const float* __restrict__ att_w,
    const float* __restrict__ gamma, const float* __restrict__ beta,
    float* __restrict__ sq, float* __restrict__ sk)
{
    const int wave = threadIdx.x >> 6;
    const int lane = threadIdx.x & 63;
    const int row  = blockIdx.x * 4 + wave;          // [0, B*N)

    const float2 x = ((const float2*)(emb + (size_t)row * Dq))[lane];

    float s = x.x + x.y;
    #pragma unroll
    for (int off = 32; off > 0; off >>= 1) s += __shfl_xor(s, off);
    const float mu = s * (1.0f / Dq);

    const float d0 = x.x - mu, d1 = x.y - mu;
    float v = d0 * d0 + d1 * d1;
    #pragma unroll
    for (int off = 32; off > 0; off >>= 1) v += __shfl_xor(v, off);
    const float rstd = rsqrtf(v * (1.0f / Dq) + LN_EPS);

    const float2 g  = ((const float2*)gamma)[lane];
    const float2 bt = ((const float2*)beta)[lane];
    const float ln0 = d0 * rstd * g.x + bt.x;
    const float ln1 = d1 * rstd * g.y + bt.y;

    const float2 wq = ((const float2*)att_w)[lane];
    const float2 wk = ((const float2*)(att_w + Dq))[lane];
    float pq = ln0 * wq.x + ln1 * wq.y;
    float pk = ln0 * wk.x + ln1 * wk.y;
    #pragma unroll
    for (int off = 32; off > 0; off >>= 1) {
        pq += __shfl_xor(pq, off);
        pk += __shfl_xor(pk, off);
    }
    if (lane == 0) { sq[row] = pq; sk[row] = pk; }
}

// ---------------- Kernel 2: leaky-relu logits + softmax over j ----------------
// One block (256 threads) per (b,i) row; each thread handles 2 j's.
__global__ void __launch_bounds__(256) softmax_kernel(
    const float* __restrict__ sq, const float* __restrict__ sk,
    const float* __restrict__ att_b, float* __restrict__ alphas)
{
    const int row = blockIdx.x;       // b*N + i
    const int b   = row >> 9;         // N = 512
    const int t   = threadIdx.x;
    const int wave = t >> 6, lane = t & 63;

    const float si = sq[row] + att_b[0];
    const float* skb = sk + b * Nq;

    float x0 = si + skb[t];
    float x1 = si + skb[t + 256];
    const float l0 = (x0 >= 0.0f) ? x0 : LEAKY * x0;
    const float l1 = (x1 >= 0.0f) ? x1 : LEAKY * x1;

    __shared__ float redm[4];
    __shared__ float reds[4];

    float m = fmaxf(l0, l1);
    #pragma unroll
    for (int off = 32; off > 0; off >>= 1) m = fmaxf(m, __shfl_xor(m, off));
    if (lane == 0) redm[wave] = m;
    __syncthreads();
    m = fmaxf(fmaxf(redm[0], redm[1]), fmaxf(redm[2], redm[3]));

    const float e0 = __expf(l0 - m);
    const float e1 = __expf(l1 - m);
    float s = e0 + e1;
    #pragma unroll
    for (int off = 32; off > 0; off >>= 1) s += __shfl_xor(s, off);
    if (lane == 0) reds[wave] = s;
    __syncthreads();
    s = reds[0] + reds[1] + reds[2] + reds[3];

    const float inv = 1.0f / s;
    float* arow = alphas + (size_t)row * Nq;
    arow[t]       = e0 * inv;
    arow[t + 256] = e1 * inv;
}

// ---------------- Kernel 3: value outer product ----------------
// One block (256 threads) per (b,i). Row emb[b,i,:] is 32 float4; thread t
// handles d4 = t&31, j_local = t>>5 (8 j's per iteration). Stores are fully
// coalesced: 256 consecutive float4 = 4 KB contiguous per iteration.
__global__ void __launch_bounds__(256) value_kernel(
    const float* __restrict__ emb, float* __restrict__ value)
{
    const int row = blockIdx.x;       // b*N + i
    const int b   = row >> 9;
    const int t   = threadIdx.x;
    const int d4  = t & 31;
    const int jl  = t >> 5;

    const float4 a = ((const float4*)(emb + (size_t)row * Dq))[d4];
    const float4* __restrict__ eb4 = (const float4*)(emb + (size_t)b * Nq * Dq);
    float4* __restrict__ out = (float4*)(value + (size_t)row * Nq * Dq);

    for (int j0 = 0; j0 < Nq; j0 += 8) {
        const int j = j0 + jl;
        const float4 v = eb4[j * 32 + d4];
        float4 r;
        r.x = a.x * v.x; r.y = a.y * v.y; r.z = a.z * v.z; r.w = a.w * v.w;
        out[(size_t)j * 32 + d4] = r;
    }
}

extern "C" void kernel_launch(void* const* d_in, const int* in_sizes, int n_in,
                              void* d_out, int out_size, void* d_ws, size_t ws_size,
                              hipStream_t stream) {
    const float* emb    = (const float*)d_in[0];
    const float* att_w  = (const float*)d_in[1];
    const float* att_b  = (const float*)d_in[2];
    const float* gamma  = (const float*)d_in[3];
    const float* beta   = (const float*)d_in[4];

    float* alphas = (float*)d_out;                              // B*N*N
    float* value  = (float*)d_out + (size_t)Bq * Nq * Nq;       // B*N*N*D

    float* sq = (float*)d_ws;           // B*N
    float* sk = sq + Bq * Nq;           // B*N

    scores_kernel<<<Bq * Nq / 4, 256, 0, stream>>>(emb, att_w, gamma, beta, sq, sk);
    softmax_kernel<<<Bq * Nq, 256, 0, stream>>>(sq, sk, att_b, alphas);
    value_kernel<<<Bq * Nq, 256, 0, stream>>>(emb, value);
}